// Round 1
// baseline (38.281 us; speedup 1.0000x reference)
//
#include <hip/hip_runtime.h>

#define NEGV (-1e9f)

// One wave (64 lanes) per graph; 4 graphs per 256-thread block.
// Stage 1: lane k computes A[k] = glob·W1g[:,k], P[i][k] = g_i·W1i[:,k],
//          Q[j][k] = g_j·W1j[:,k]  (17 fp32 accumulators per lane).
// Stage 2: lane p=(i*8+j) computes sum_k relu(A+P_i+Q_j+b1)[k]*W2[k] via LDS.
__global__ __launch_bounds__(256, 2) void dock_kernel(
    const float* __restrict__ nodes,   // [B*64, 128]
    const float* __restrict__ glob,    // [B, 128]
    const int*   __restrict__ dock,    // [B, 8, 8] (0/1)
    const float* __restrict__ W1,      // [384, 64]
    const float* __restrict__ b1,      // [64]
    const float* __restrict__ W2,      // [64]
    const float* __restrict__ b2,      // [1]
    float* __restrict__ out)           // [B, 64]
{
    const int lane = threadIdx.x & 63;
    const int wid  = __builtin_amdgcn_readfirstlane(threadIdx.x >> 6);
    const int b    = blockIdx.x * 4 + wid;

    // rows: 0 = A, 1..8 = P[i], 9..16 = Q[j]; pad to 72 floats -> 2-way max
    __shared__ float lds[4][17][72];

    const float* gbase = nodes + (size_t)b * (64 * 128);  // first 8 rows = group nodes
    const float* gl    = glob  + (size_t)b * 128;

    float accA = 0.f;
    float accP[8], accQ[8];
#pragma unroll
    for (int i = 0; i < 8; ++i) { accP[i] = 0.f; accQ[i] = 0.f; }

    const int k = lane;
    for (int f = 0; f < 128; f += 4) {
        // wave-uniform addresses -> scalar loads (SGPR operands)
        const float4 gl4 = *reinterpret_cast<const float4*>(gl + f);
        float4 gv4[8];
#pragma unroll
        for (int i = 0; i < 8; ++i)
            gv4[i] = *reinterpret_cast<const float4*>(gbase + i * 128 + f);
#pragma unroll
        for (int u = 0; u < 4; ++u) {
            const float wg = W1[(f + u) * 64 + k];          // coalesced, L2-hot
            const float wi = W1[(128 + f + u) * 64 + k];
            const float wj = W1[(256 + f + u) * 64 + k];
            const float glu = (&gl4.x)[u];
            accA = fmaf(glu, wg, accA);
#pragma unroll
            for (int i = 0; i < 8; ++i) {
                const float gv = (&gv4[i].x)[u];
                accP[i] = fmaf(gv, wi, accP[i]);
                accQ[i] = fmaf(gv, wj, accQ[i]);
            }
        }
    }

    lds[wid][0][k] = accA;
#pragma unroll
    for (int i = 0; i < 8; ++i) {
        lds[wid][1 + i][k] = accP[i];
        lds[wid][9 + i][k] = accQ[i];
    }
    __syncthreads();   // ensure cross-lane LDS visibility

    // stage 2: lane p = pair (i,j)
    const int p = lane;
    const int i = p >> 3;
    const int j = p & 7;
    const float* ldsw = &lds[wid][0][0];

    float s = 0.f;
#pragma unroll
    for (int kk = 0; kk < 64; kk += 4) {
        const float4 a4 = *reinterpret_cast<const float4*>(ldsw + kk);
        const float4 p4 = *reinterpret_cast<const float4*>(ldsw + (1 + i) * 72 + kk);
        const float4 q4 = *reinterpret_cast<const float4*>(ldsw + (9 + j) * 72 + kk);
        const float4 b4 = *reinterpret_cast<const float4*>(b1 + kk);   // uniform -> s_load
        const float4 w4 = *reinterpret_cast<const float4*>(W2 + kk);   // uniform -> s_load
#pragma unroll
        for (int u = 0; u < 4; ++u) {
            float h = (&a4.x)[u] + (&p4.x)[u] + (&q4.x)[u] + (&b4.x)[u];
            h = fmaxf(h, 0.f);
            s = fmaf(h, (&w4.x)[u], s);
        }
    }
    s += b2[0];

    const int idx = b * 64 + p;
    const bool keep = (i != j) && (dock[idx] != 0);
    out[idx] = keep ? s : NEGV;
}

extern "C" void kernel_launch(void* const* d_in, const int* in_sizes, int n_in,
                              void* d_out, int out_size, void* d_ws, size_t ws_size,
                              hipStream_t stream) {
    const float* nodes = (const float*)d_in[0];
    const float* glob  = (const float*)d_in[1];
    // d_in[2] = group_mask_nodes (unused: group nodes are rows [b*64, b*64+8))
    // d_in[3] = batch (unused: rows are sorted by graph)
    const int*   dock  = (const int*)d_in[4];
    const float* W1    = (const float*)d_in[5];
    const float* b1    = (const float*)d_in[6];
    const float* W2    = (const float*)d_in[7];
    const float* b2    = (const float*)d_in[8];
    float* out = (float*)d_out;

    const int B = in_sizes[1] / 128;   // 4096
    dock_kernel<<<dim3(B / 4), dim3(256), 0, stream>>>(
        nodes, glob, dock, W1, b1, W2, b2, out);
}

// Round 2
// 18.865 us; speedup vs baseline: 2.0293x; 2.0293x over previous
//
#include <hip/hip_runtime.h>
#include <hip/hip_bf16.h>

#define NEGV (-1e9f)

typedef __attribute__((ext_vector_type(8))) short short8;
typedef __attribute__((ext_vector_type(4))) float f32x4;

#define MFMA16(a, b, c) __builtin_amdgcn_mfma_f32_16x16x32_bf16(a, b, c, 0, 0, 0)
#define LDS_PTR(p) ((__attribute__((address_space(3))) void*)(p))
#define GLB_PTR(p) ((const __attribute__((address_space(1))) void*)(p))

__device__ __forceinline__ unsigned short f2bf(float x) {
    union { __hip_bfloat16 h; unsigned short u; } c;
    c.h = __float2bfloat16(x);
    return c.u;
}

__device__ __forceinline__ short8 pack2(f32x4 a, f32x4 b) {
    short8 r;
    r[0] = (short)f2bf(a[0]); r[1] = (short)f2bf(a[1]);
    r[2] = (short)f2bf(a[2]); r[3] = (short)f2bf(a[3]);
    r[4] = (short)f2bf(b[0]); r[5] = (short)f2bf(b[1]);
    r[6] = (short)f2bf(b[2]); r[7] = (short)f2bf(b[3]);
    return r;
}

// ---- prep: transpose W1 [384][64] fp32 -> bf16 LDS image in ws ----
// ws layout (bytes): [0,32768): Wt_pq  rows n in [0,128): n<64 -> W1i col n, n>=64 -> W1j col n-64
//                    [32768,49152): Wt_g rows n in [0,64):  W1g col n
// Each row: 128 k-elements as 16 units of 16B, unit stored at (u ^ (n&7)) -- the
// exact (pre-swizzled) image the main kernel copies into LDS linearly.
__global__ void dock_prep(const float* __restrict__ W1, unsigned short* __restrict__ wsw) {
    int o = blockIdx.x * 256 + threadIdx.x;          // 0..24575
    if (o < 16384) {                                  // Wt_pq
        int n = o >> 7, k = o & 127;
        float v = (n < 64) ? W1[(128 + k) * 64 + n] : W1[(256 + k) * 64 + (n - 64)];
        int byte = n * 256 + ((((k >> 3)) ^ (n & 7)) << 4) + (k & 7) * 2;
        wsw[byte >> 1] = f2bf(v);
    } else {                                          // Wt_g
        int o2 = o - 16384;
        int n = o2 >> 7, k = o2 & 127;
        float v = W1[k * 64 + n];
        int byte = 32768 + n * 256 + ((((k >> 3)) ^ (n & 7)) << 4) + (k & 7) * 2;
        wsw[byte >> 1] = f2bf(v);
    }
}

// ---- main: 4 graphs per 256-thread block (4 waves), MFMA stage 1 ----
__global__ __launch_bounds__(256, 2) void dock_main(
    const float* __restrict__ nodes,   // [B*64,128]
    const float* __restrict__ glob,    // [B,128]
    const int*   __restrict__ dock,    // [B,64]
    const float* __restrict__ b1,      // [64]
    const float* __restrict__ W2,      // [64]
    const float* __restrict__ b2,      // [1]
    const unsigned char* __restrict__ wsw,  // 48KB bf16 weight image
    float* __restrict__ out)           // [B,64]
{
    // LDS map (60KB): gA 8KB | gGl 4KB | weights 48KB (overlaid by sPQ/sA after MFMA)
    __shared__ __align__(16) unsigned char smem[61440];
    unsigned char* gA    = smem;            // bf16 [32 rows][256B], swizzled units
    unsigned char* gGl   = smem + 8192;     // bf16 [16 rows][256B], rows 4..15 zero
    unsigned char* wbase = smem + 12288;    // Wt_pq 32KB then Wt_g 16KB
    float* sPQ = (float*)(smem + 12288);          // f32 [32][132]
    float* sA  = (float*)(smem + 12288 + 16896);  // f32 [4][68]

    const int t    = threadIdx.x;
    const int lane = t & 63;
    const int w    = __builtin_amdgcn_readfirstlane(t >> 6);
    const int b0   = blockIdx.x * 4;

    // -- stage weights: wave w copies 12KB via global_load_lds (16B/lane, linear)
#pragma unroll
    for (int c = 0; c < 12; ++c) {
        int off = (w * 12 + c) * 1024;
        __builtin_amdgcn_global_load_lds(GLB_PTR(wsw + off + lane * 16),
                                         LDS_PTR(wbase + off), 16, 0, 0);
    }

    // -- stage group rows: [32][128] fp32 -> bf16, swizzled. t: row=t>>3, cols (t&7)*16..+15
    {
        int r = t >> 3, c0 = (t & 7) * 16;
        const f32x4* s4 = (const f32x4*)(nodes + ((size_t)(b0 + (r >> 3)) * 64 + (r & 7)) * 128 + c0);
        f32x4 f0 = s4[0], f1 = s4[1], f2 = s4[2], f3 = s4[3];
        int u0 = c0 >> 3;                       // 16B unit index (8 bf16 per unit)
        *(short8*)(gA + r * 256 + ((u0 ^ (r & 7)) << 4))       = pack2(f0, f1);
        *(short8*)(gA + r * 256 + (((u0 + 1) ^ (r & 7)) << 4)) = pack2(f2, f3);
    }
    // -- stage glob rows: [16][128], rows>=4 zero. t: row=t>>4, cols (t&15)*8..+7
    {
        int r = t >> 4, c0 = (t & 15) * 8;
        short8 v = (short8)0;
        if (r < 4) {
            const f32x4* s4 = (const f32x4*)(glob + (size_t)(b0 + r) * 128 + c0);
            v = pack2(s4[0], s4[1]);
        }
        *(short8*)(gGl + r * 256 + (((c0 >> 3) ^ (r & 7)) << 4)) = v;
    }
    __syncthreads();   // drains vmcnt (global_load_lds) + lgkm

    // -- MFMA: PQ = G[32x128] x Wt_pq^T -> [32][128]; A = Gl[16x128] x Wt_g^T -> [16][64]
    // wave w owns PQ cols [32w,32w+32) and A cols [16w,16w+16)
    const int lr = lane & 15, lg = lane >> 4;
    f32x4 accPQ00 = (f32x4)0.f, accPQ01 = (f32x4)0.f;
    f32x4 accPQ10 = (f32x4)0.f, accPQ11 = (f32x4)0.f;
    f32x4 accA    = (f32x4)0.f;
    const unsigned char* wPQ = wbase;
    const unsigned char* wG  = wbase + 32768;
#pragma unroll
    for (int kt = 0; kt < 4; ++kt) {
        const int sw = (((kt * 4 + lg)) ^ (lr & 7)) << 4;   // row&7 == lr&7 for all rows used
        short8 aG0 = *(const short8*)(gA + (lr)       * 256 + sw);
        short8 aG1 = *(const short8*)(gA + (16 + lr)  * 256 + sw);
        short8 bq0 = *(const short8*)(wPQ + (w * 32 + lr)      * 256 + sw);
        short8 bq1 = *(const short8*)(wPQ + (w * 32 + 16 + lr) * 256 + sw);
        short8 aGl = *(const short8*)(gGl + lr * 256 + sw);
        short8 bg  = *(const short8*)(wG + (w * 16 + lr) * 256 + sw);
        accPQ00 = MFMA16(aG0, bq0, accPQ00);
        accPQ01 = MFMA16(aG0, bq1, accPQ01);
        accPQ10 = MFMA16(aG1, bq0, accPQ10);
        accPQ11 = MFMA16(aG1, bq1, accPQ11);
        accA    = MFMA16(aGl, bg,  accA);
    }
    __syncthreads();   // all waves done reading weight LDS before overlay writes

    // -- spill C fragments: C[row=(lane>>4)*4+r][col=lane&15] (verified layout)
#pragma unroll
    for (int r = 0; r < 4; ++r) {
        sPQ[(lg * 4 + r) * 132      + (w * 32 + lr)]      = accPQ00[r];
        sPQ[(lg * 4 + r) * 132      + (w * 32 + 16 + lr)] = accPQ01[r];
        sPQ[(16 + lg * 4 + r) * 132 + (w * 32 + lr)]      = accPQ10[r];
        sPQ[(16 + lg * 4 + r) * 132 + (w * 32 + 16 + lr)] = accPQ11[r];
    }
    if (lg == 0) {
#pragma unroll
        for (int r = 0; r < 4; ++r)
            sA[r * 68 + w * 16 + lr] = accA[r];   // graph r, hidden col w*16+lr
    }
    __syncthreads();

    // -- stage 2: wave w -> graph b0+w; lane p=(i,j)
    const int i = lane >> 3, j = lane & 7;
    const float* aRow = sA + w * 68;
    const float* pRow = sPQ + (w * 8 + i) * 132;        // P = cols [0,64)
    const float* qRow = sPQ + (w * 8 + j) * 132 + 64;   // Q = cols [64,128)

    float s = 0.f;
#pragma unroll
    for (int kk = 0; kk < 64; kk += 4) {
        f32x4 a4 = *(const f32x4*)(aRow + kk);
        f32x4 p4 = *(const f32x4*)(pRow + kk);
        f32x4 q4 = *(const f32x4*)(qRow + kk);
        f32x4 bb = *(const f32x4*)(b1 + kk);
        f32x4 w4 = *(const f32x4*)(W2 + kk);
#pragma unroll
        for (int u = 0; u < 4; ++u) {
            float h = a4[u] + p4[u] + q4[u] + bb[u];
            h = fmaxf(h, 0.f);
            s = fmaf(h, w4[u], s);
        }
    }
    s += b2[0];

    const int idx = (b0 + w) * 64 + lane;
    out[idx] = ((i != j) && (dock[idx] != 0)) ? s : NEGV;
}

extern "C" void kernel_launch(void* const* d_in, const int* in_sizes, int n_in,
                              void* d_out, int out_size, void* d_ws, size_t ws_size,
                              hipStream_t stream) {
    const float* nodes = (const float*)d_in[0];
    const float* glob  = (const float*)d_in[1];
    // d_in[2] group_mask_nodes, d_in[3] batch: unused (rows sorted, 8 group rows/graph)
    const int*   dock  = (const int*)d_in[4];
    const float* W1    = (const float*)d_in[5];
    const float* b1    = (const float*)d_in[6];
    const float* W2    = (const float*)d_in[7];
    const float* b2    = (const float*)d_in[8];
    float* out = (float*)d_out;

    const int B = in_sizes[1] / 128;            // 4096
    unsigned short* wsw = (unsigned short*)d_ws; // needs 48KB (ws_size ample)

    dock_prep<<<dim3(96), dim3(256), 0, stream>>>(W1, wsw);
    dock_main<<<dim3(B / 4), dim3(256), 0, stream>>>(
        nodes, glob, dock, b1, W2, b2, (const unsigned char*)wsw, out);
}

// Round 3
// 14.933 us; speedup vs baseline: 2.5635x; 1.2633x over previous
//
#include <hip/hip_runtime.h>
#include <hip/hip_bf16.h>

#define NEGV (-1e9f)

typedef __attribute__((ext_vector_type(8))) short short8;
typedef __attribute__((ext_vector_type(4))) float f32x4;

#define MFMA16(a, b, c) __builtin_amdgcn_mfma_f32_16x16x32_bf16(a, b, c, 0, 0, 0)

__device__ __forceinline__ unsigned short f2bf(float x) {
    union { __hip_bfloat16 h; unsigned short u; } c;
    c.h = __float2bfloat16(x);
    return c.u;
}

__device__ __forceinline__ short8 pack2(f32x4 a, f32x4 b) {
    short8 r;
    r[0] = (short)f2bf(a[0]); r[1] = (short)f2bf(a[1]);
    r[2] = (short)f2bf(a[2]); r[3] = (short)f2bf(a[3]);
    r[4] = (short)f2bf(b[0]); r[5] = (short)f2bf(b[1]);
    r[6] = (short)f2bf(b[2]); r[7] = (short)f2bf(b[3]);
    return r;
}

__device__ __forceinline__ short8 pack8(const float* v) {
    short8 r;
#pragma unroll
    for (int i = 0; i < 8; ++i) r[i] = (short)f2bf(v[i]);
    return r;
}

// Single kernel: 4 graphs per 256-thread block (4 waves), grid = B/4.
// Weights live in REGISTERS (per-wave B-fragments gathered from L2-hot W1);
// LDS = 18KB: staging region (gA 8K | gGl 4K) overlaid by spill (sPQ+sA) after
// a barrier -> ~4 blocks/CU resident.
__global__ __launch_bounds__(256, 4) void dock_main(
    const float* __restrict__ nodes,   // [B*64,128]
    const float* __restrict__ glob,    // [B,128]
    const int*   __restrict__ dock,    // [B,64]
    const float* __restrict__ W1,      // [384,64]
    const float* __restrict__ b1,      // [64]
    const float* __restrict__ W2,      // [64]
    const float* __restrict__ b2,      // [1]
    float* __restrict__ out)           // [B,64]
{
    __shared__ __align__(16) unsigned char smem[18048];
    unsigned char* gA  = smem;                 // bf16 [32 rows][256B], swizzled units
    unsigned char* gGl = smem + 8192;          // bf16 [16 rows][256B], rows 4..15 zero
    float* sPQ = (float*)smem;                 // f32 [32][132]  (overlay, post-barrier)
    float* sA  = (float*)(smem + 16896);       // f32 [4][68]

    const int t    = threadIdx.x;
    const int lane = t & 63;
    const int w    = __builtin_amdgcn_readfirstlane(t >> 6);
    const int b0   = blockIdx.x * 4;
    const int lr   = lane & 15, lg = lane >> 4;

    // ---- gather per-wave B-fragments from W1 (L2-hot), fp32 -> bf16 registers.
    // B-fragment (verified in r2's passing kernel): lane l, elem i holds
    // W1t[n][k], n = col block + (l&15), k = kt*32 + (l>>4)*8 + i.
    short8 bq0f[4], bq1f[4], bgf[4];
    {
        const int n0 = w * 32 + lr;            // PQ ntile 0: n in [0,128)
        const int n1 = n0 + 16;                // PQ ntile 1
        const int ng = w * 16 + lr;            // G ntile: n in [0,64)
        const float* Wp0 = (n0 < 64) ? W1 + 128 * 64 + n0 : W1 + 256 * 64 + (n0 - 64);
        const float* Wp1 = (n1 < 64) ? W1 + 128 * 64 + n1 : W1 + 256 * 64 + (n1 - 64);
        const float* Wpg = W1 + ng;
#pragma unroll
        for (int kt = 0; kt < 4; ++kt) {
            float v0[8], v1[8], vg[8];
#pragma unroll
            for (int i = 0; i < 8; ++i) {
                const int k = kt * 32 + lg * 8 + i;
                v0[i] = Wp0[k * 64];
                v1[i] = Wp1[k * 64];
                vg[i] = Wpg[k * 64];
            }
            bq0f[kt] = pack8(v0);
            bq1f[kt] = pack8(v1);
            bgf[kt]  = pack8(vg);
        }
    }

    // ---- stage group rows: [32][128] fp32 -> bf16, swizzled units.
    {
        int r = t >> 3, c0 = (t & 7) * 16;
        const f32x4* s4 = (const f32x4*)(nodes + ((size_t)(b0 + (r >> 3)) * 64 + (r & 7)) * 128 + c0);
        f32x4 f0 = s4[0], f1 = s4[1], f2 = s4[2], f3 = s4[3];
        int u0 = c0 >> 3;
        *(short8*)(gA + r * 256 + ((u0 ^ (r & 7)) << 4))       = pack2(f0, f1);
        *(short8*)(gA + r * 256 + (((u0 + 1) ^ (r & 7)) << 4)) = pack2(f2, f3);
    }
    // ---- stage glob rows: [16][128], rows>=4 zero.
    {
        int r = t >> 4, c0 = (t & 15) * 8;
        short8 v = (short8)0;
        if (r < 4) {
            const f32x4* s4 = (const f32x4*)(glob + (size_t)(b0 + r) * 128 + c0);
            v = pack2(s4[0], s4[1]);
        }
        *(short8*)(gGl + r * 256 + (((c0 >> 3) ^ (r & 7)) << 4)) = v;
    }
    __syncthreads();

    // ---- MFMA: PQ[32x128] = G x W1ij^T ; A[16x64] = Gl x W1g^T
    f32x4 acc00 = (f32x4)0.f, acc01 = (f32x4)0.f;
    f32x4 acc10 = (f32x4)0.f, acc11 = (f32x4)0.f;
    f32x4 accA  = (f32x4)0.f;
#pragma unroll
    for (int kt = 0; kt < 4; ++kt) {
        const int sw = ((kt * 4 + lg) ^ (lr & 7)) << 4;
        short8 aG0 = *(const short8*)(gA + lr * 256 + sw);
        short8 aG1 = *(const short8*)(gA + (16 + lr) * 256 + sw);
        short8 aGl = *(const short8*)(gGl + lr * 256 + sw);
        acc00 = MFMA16(aG0, bq0f[kt], acc00);
        acc01 = MFMA16(aG0, bq1f[kt], acc01);
        acc10 = MFMA16(aG1, bq0f[kt], acc10);
        acc11 = MFMA16(aG1, bq1f[kt], acc11);
        accA  = MFMA16(aGl, bgf[kt],  accA);
    }
    __syncthreads();   // all waves done reading staging LDS before overlay writes

    // ---- spill C fragments: C[row=(lane>>4)*4+r][col=lane&15]
#pragma unroll
    for (int r = 0; r < 4; ++r) {
        sPQ[(lg * 4 + r) * 132      + (w * 32 + lr)]      = acc00[r];
        sPQ[(lg * 4 + r) * 132      + (w * 32 + 16 + lr)] = acc01[r];
        sPQ[(16 + lg * 4 + r) * 132 + (w * 32 + lr)]      = acc10[r];
        sPQ[(16 + lg * 4 + r) * 132 + (w * 32 + 16 + lr)] = acc11[r];
    }
    if (lg == 0) {
#pragma unroll
        for (int r = 0; r < 4; ++r)
            sA[r * 68 + w * 16 + lr] = accA[r];   // graph r, hidden col w*16+lr
    }
    __syncthreads();

    // ---- stage 2: wave w -> graph b0+w; lane p=(i,j)
    const int i = lane >> 3, j = lane & 7;
    const float* aRow = sA + w * 68;
    const float* pRow = sPQ + (w * 8 + i) * 132;        // P = cols [0,64)
    const float* qRow = sPQ + (w * 8 + j) * 132 + 64;   // Q = cols [64,128)

    float s = 0.f;
#pragma unroll
    for (int kk = 0; kk < 64; kk += 4) {
        f32x4 a4 = *(const f32x4*)(aRow + kk);
        f32x4 p4 = *(const f32x4*)(pRow + kk);
        f32x4 q4 = *(const f32x4*)(qRow + kk);
        f32x4 bb = *(const f32x4*)(b1 + kk);
        f32x4 w4 = *(const f32x4*)(W2 + kk);
#pragma unroll
        for (int u = 0; u < 4; ++u) {
            float h = a4[u] + p4[u] + q4[u] + bb[u];
            h = fmaxf(h, 0.f);
            s = fmaf(h, w4[u], s);
        }
    }
    s += b2[0];

    const int idx = (b0 + w) * 64 + lane;
    out[idx] = ((i != j) && (dock[idx] != 0)) ? s : NEGV;
}

extern "C" void kernel_launch(void* const* d_in, const int* in_sizes, int n_in,
                              void* d_out, int out_size, void* d_ws, size_t ws_size,
                              hipStream_t stream) {
    const float* nodes = (const float*)d_in[0];
    const float* glob  = (const float*)d_in[1];
    // d_in[2] group_mask_nodes, d_in[3] batch: unused (rows sorted, 8 group rows/graph)
    const int*   dock  = (const int*)d_in[4];
    const float* W1    = (const float*)d_in[5];
    const float* b1    = (const float*)d_in[6];
    const float* W2    = (const float*)d_in[7];
    const float* b2    = (const float*)d_in[8];
    float* out = (float*)d_out;

    const int B = in_sizes[1] / 128;   // 4096
    dock_main<<<dim3(B / 4), dim3(256), 0, stream>>>(
        nodes, glob, dock, W1, b1, W2, b2, out);
}